// Round 9
// baseline (362.824 us; speedup 1.0000x reference)
//
#include <hip/hip_runtime.h>

// VQ-VAE vector quantizer, R26: R24 + paired phases (16 barriers) done register-safe,
// + split MFMA chains + setprio.
// R25 post-mortem: pairing via back-to-back inlined computeG let the compiler co-
// schedule two groups' full state (2x accum AGPR + 2x B frags) -> unified-file
// overflow -> 128-pinned arch VGPR + 515MB scratch. Fix: same 16-barrier pairing but
// groups SEQUENTIAL inside the phase with sched_barrier(0) between them — live state
// stays single-group (R24's proven footprint). Also: a2 8-deep chain split into two
// 4-deep chains (+16 AGPR only), s_setprio(1) around MFMA cluster (T5: same-SIMD
// waves are from different blocks/phases).
// Structure: R18 geometry, B staged via global_load_lds(16B) into LDS ring-8 in
// MFMA-fragment order (prep pre-tiles), counted vmcnt(12) + raw s_barrier per phase
// (6 VMEM/wave/phase, distance 2 phases), A-preamble drained by vmcnt(0).
// Exactness: streaming top-2, strict-< lowest-idx, near-ties (<1e-3) fp32 rescan.
// out (fp32 concat): [ loss(1) | quantized NCHW (4194304) | indices as float (65536) ]

#define DIMS   64
#define HW     4096
#define NPTS   65536
#define NCODES 1024
#define NPB    128
#define QOFF   1
#define IOFF   (1 + NPTS * DIMS)
#define EPSGAP 1.0e-3f

typedef unsigned int uint;
typedef unsigned short ushort;
typedef unsigned long long ull;
typedef __attribute__((ext_vector_type(8))) short short8;
typedef __attribute__((ext_vector_type(16))) float f32x16;

__device__ __forceinline__ ushort bf16_rne(float f) {
    uint u = __float_as_uint(f);
    uint r = u + 0x7FFFu + ((u >> 16) & 1u);
    return (ushort)(r >> 16);
}
__device__ __forceinline__ float bf16f(ushort h) { return __uint_as_float(((uint)h) << 16); }

__device__ __forceinline__ void gload16(const void* g, void* l) {
    __builtin_amdgcn_global_load_lds(
        (const __attribute__((address_space(1))) void*)g,
        (__attribute__((address_space(3))) void*)l, 16, 0, 0);
}

// ---- prep: emb fp32 -> tiled {Eh, El} in MFMA-fragment order + hsq = 0.5||e||^2.
// Element (code c, dim d) -> ushort index g*2048 + ks*512 + (hh*32 + (c&31))*8 + (d&7),
// where g=c>>5, ks=d>>4, hh=(d>>3)&1. Lane l of group g then reads its fragment at
// [g][ks*512 + l*8] — linear in lane, so global_load_lds staging needs no swizzle.
__global__ void vq_prep(const float* __restrict__ emb, ushort* __restrict__ Eh,
                        ushort* __restrict__ El, float* __restrict__ hsq,
                        float* __restrict__ out)
{
    const int t = blockIdx.x * 256 + threadIdx.x;      // 0..16383 = code*16 + dim-group
    if (t == 0) out[0] = 0.f;
    float4 v = ((const float4*)emb)[t];
    ushort h0 = bf16_rne(v.x), h1 = bf16_rne(v.y), h2 = bf16_rne(v.z), h3 = bf16_rne(v.w);
    ushort l0 = bf16_rne(v.x - bf16f(h0)), l1 = bf16_rne(v.y - bf16f(h1));
    ushort l2 = bf16_rne(v.z - bf16f(h2)), l3 = bf16_rne(v.w - bf16f(h3));
    uint2 hp, lp;
    hp.x = (uint)h0 | ((uint)h1 << 16); hp.y = (uint)h2 | ((uint)h3 << 16);
    lp.x = (uint)l0 | ((uint)l1 << 16); lp.y = (uint)l2 | ((uint)l3 << 16);
    const int c = t >> 4, q = t & 15;
    const int g = c >> 5, nn = c & 31;
    const int d0 = q * 4;
    const int ks = d0 >> 4, hh = (d0 >> 3) & 1, j0 = d0 & 7;   // j0 in {0,4}
    const int base = g * 2048 + ks * 512 + (hh * 32 + nn) * 8 + j0;
    *(uint2*)(Eh + base) = hp;
    *(uint2*)(El + base) = lp;
    // hsq: 16 consecutive lanes hold one code's 16 float4s -> xor-shuffle reduce
    float pe = fmaf(v.x, v.x, fmaf(v.y, v.y, fmaf(v.z, v.z, v.w * v.w)));
    pe += __shfl_xor(pe, 1); pe += __shfl_xor(pe, 2);
    pe += __shfl_xor(pe, 4); pe += __shfl_xor(pe, 8);
    if ((t & 15) == 0) hsq[t >> 4] = 0.5f * pe;
}

__launch_bounds__(256, 2)
__global__ void vq_main(const float* __restrict__ in, const float* __restrict__ emb,
                        const ushort* __restrict__ Ehw, const ushort* __restrict__ Elw,
                        const float* __restrict__ hsqw, float* __restrict__ out)
{
    __shared__ ushort sEh[8][2048];                    // 8-slot ring, 4KB per slot
    __shared__ ushort sEl[8][2048];
    __shared__ float sv1[NPB];
    __shared__ float sv2[NPB];
    __shared__ int   si1[NPB];
    __shared__ ull   msk[2];
    __shared__ int   lst[1 + NPB];
    __shared__ float lred[4];

    const int tid = threadIdx.x;
    const int lane = tid & 63, w = tid >> 6;
    const int nn = lane & 31;                          // row (A) / col (B) within 32
    const int h  = lane >> 5;                          // k-half selector
    const int n0 = blockIdx.x * NPB;
    const int b = n0 >> 12, off = n0 & 4095;           // 128 | 4096: never crosses a batch
    const float* xbase = in + (size_t)b * (DIMS * HW) + off;

    // ---- A fragments: wave's 32 points, hi+lo bf16; k = ks*16 + 8h + j
    short8 Ah[4], Al[4];
    {
        const int p = w * 32 + nn;
        #pragma unroll
        for (int ks = 0; ks < 4; ++ks) {
            union { ushort u[8]; short8 v; } th, tl;
            #pragma unroll
            for (int j = 0; j < 8; ++j) {
                float x = xbase[(ks * 16 + h * 8 + j) * HW + p];
                ushort hh = bf16_rne(x);
                th.u[j] = hh;
                tl.u[j] = bf16_rne(x - bf16f(hh));
            }
            Ah[ks] = th.v; Al[ks] = tl.v;
        }
    }
    asm volatile("s_waitcnt vmcnt(0)" ::: "memory");   // counted region starts clean
    __builtin_amdgcn_sched_barrier(0);

    float v1s[16], v2s[16]; int i1s[16];
    #pragma unroll
    for (int r = 0; r < 16; ++r) { v1s[r] = 1e30f; v2s[r] = 1e30f; i1s[r] = 0; }

    // Phase s covers groups {2s, 2s+1} -> ring slots {(2s)&7, (2s+1)&7} (16KB/phase).
    // Wave roles: w>>1 selects group, w&1 selects table. 4 gload16 per wave per phase.
    auto stagePhase = [&](int s) {
        const int g0 = (2 * s < 32) ? 2 * s : 31;      // tail: dummy re-stage of grp 31
        const int g1 = (2 * s + 1 < 32) ? 2 * s + 1 : 31;
        const int gg = (w >> 1) ? g1 : g0;
        const int sl = (w >> 1) ? ((2 * s + 1) & 7) : ((2 * s) & 7);
        if ((w & 1) == 0) {
            const ushort* src = Ehw + (size_t)gg * 2048;
            #pragma unroll
            for (int u = 0; u < 4; ++u) gload16(src + u * 512 + lane * 8, &sEh[sl][u * 512]);
        } else {
            const ushort* src = Elw + (size_t)gg * 2048;
            #pragma unroll
            for (int u = 0; u < 4; ++u) gload16(src + u * 512 + lane * 8, &sEl[sl][u * 512]);
        }
    };

    auto computeG = [&](int g, int buf, float HA) {
        short8 Bh[4], Bl[4];
        #pragma unroll
        for (int ks = 0; ks < 4; ++ks) {               // lane-linear ds_read_b128 x8
            Bh[ks] = *(const short8*)&sEh[buf][ks * 512 + lane * 8];
            Bl[ks] = *(const short8*)&sEl[buf][ks * 512 + lane * 8];
        }
        f32x16 a1 = {0.f,0.f,0.f,0.f,0.f,0.f,0.f,0.f,0.f,0.f,0.f,0.f,0.f,0.f,0.f,0.f};
        f32x16 a2 = {0.f,0.f,0.f,0.f,0.f,0.f,0.f,0.f,0.f,0.f,0.f,0.f,0.f,0.f,0.f,0.f};
        f32x16 a3 = {0.f,0.f,0.f,0.f,0.f,0.f,0.f,0.f,0.f,0.f,0.f,0.f,0.f,0.f,0.f,0.f};
        __builtin_amdgcn_s_setprio(1);
        #pragma unroll
        for (int ks = 0; ks < 4; ++ks)                 // chain 1: hh (4-deep)
            a1 = __builtin_amdgcn_mfma_f32_32x32x16_bf16(Ah[ks], Bh[ks], a1, 0, 0, 0);
        #pragma unroll
        for (int ks = 0; ks < 4; ++ks)                 // chain 2: hl (4-deep)
            a2 = __builtin_amdgcn_mfma_f32_32x32x16_bf16(Ah[ks], Bl[ks], a2, 0, 0, 0);
        #pragma unroll
        for (int ks = 0; ks < 4; ++ks)                 // chain 3: lh (4-deep)
            a3 = __builtin_amdgcn_mfma_f32_32x32x16_bf16(Al[ks], Bh[ks], a3, 0, 0, 0);
        __builtin_amdgcn_s_setprio(0);
        const int ca = g * 32 + nn;
        #pragma unroll
        for (int r = 0; r < 16; ++r) {                 // r -> point row (fixed lane->code)
            float d = HA - (a1[r] + a2[r] + a3[r]);
            v2s[r] = fminf(v2s[r], fmaxf(d, v1s[r]));  // exact streaming 2nd-min
            bool c2 = d < v1s[r];                      // strict: ascending g keeps lowest idx
            i1s[r] = c2 ? ca : i1s[r];
            v1s[r] = fminf(d, v1s[r]);
        }
    };

    // ---- K-loop: 16 phases x 2 groups (sequential inside a phase: sched_barrier(0)
    // keeps live state single-group — R25's spill was the two groups co-scheduled).
    // Per phase/wave: 4 gload_lds + 2 hsq = 6 VMEM (tail dummies keep count exact).
    // vmcnt(12): distance-2-phase prefetch stays in flight; phase-s data complete.
    stagePhase(0); float h0x = hsqw[0 * 32 + nn],  h0y = hsqw[1 * 32 + nn];
    stagePhase(1); float h1x = hsqw[2 * 32 + nn],  h1y = hsqw[3 * 32 + nn];
    float h2x, h2y, h3x, h3y;
    #pragma unroll 1
    for (int t = 0; t < 4; ++t) {
        const int P = 4 * t;                           // phases P..P+3 this body
        {
            const int s = P + 2;
            stagePhase(s);
            const int ga = (2 * s < 32) ? 2 * s : 31, gb = (2 * s + 1 < 32) ? 2 * s + 1 : 31;
            h2x = hsqw[ga * 32 + nn]; h2y = hsqw[gb * 32 + nn];
            asm volatile("s_waitcnt vmcnt(12)\ns_barrier" ::: "memory");
            const int g = 2 * P;
            computeG(g, g & 7, h0x);
            __builtin_amdgcn_sched_barrier(0);
            computeG(g + 1, (g + 1) & 7, h0y);
        }
        {
            const int s = P + 3;
            stagePhase(s);
            const int ga = (2 * s < 32) ? 2 * s : 31, gb = (2 * s + 1 < 32) ? 2 * s + 1 : 31;
            h3x = hsqw[ga * 32 + nn]; h3y = hsqw[gb * 32 + nn];
            asm volatile("s_waitcnt vmcnt(12)\ns_barrier" ::: "memory");
            const int g = 2 * P + 2;
            computeG(g, g & 7, h1x);
            __builtin_amdgcn_sched_barrier(0);
            computeG(g + 1, (g + 1) & 7, h1y);
        }
        {
            const int s = P + 4;
            stagePhase(s);
            const int ga = (2 * s < 32) ? 2 * s : 31, gb = (2 * s + 1 < 32) ? 2 * s + 1 : 31;
            h0x = hsqw[ga * 32 + nn]; h0y = hsqw[gb * 32 + nn];
            asm volatile("s_waitcnt vmcnt(12)\ns_barrier" ::: "memory");
            const int g = 2 * P + 4;
            computeG(g, g & 7, h2x);
            __builtin_amdgcn_sched_barrier(0);
            computeG(g + 1, (g + 1) & 7, h2y);
        }
        {
            const int s = P + 5;
            stagePhase(s);
            const int ga = (2 * s < 32) ? 2 * s : 31, gb = (2 * s + 1 < 32) ? 2 * s + 1 : 31;
            h1x = hsqw[ga * 32 + nn]; h1y = hsqw[gb * 32 + nn];
            asm volatile("s_waitcnt vmcnt(12)\ns_barrier" ::: "memory");
            const int g = 2 * P + 6;
            computeG(g, g & 7, h3x);
            __builtin_amdgcn_sched_barrier(0);
            computeG(g + 1, (g + 1) & 7, h3y);
        }
    }

    // ---- merge across the 32 code-lanes (both k-halves of a point share a half-wave)
    #pragma unroll
    for (int st = 1; st < 32; st <<= 1) {
        #pragma unroll
        for (int r = 0; r < 16; ++r) {
            float ov1 = __shfl_xor(v1s[r], st);
            float ov2 = __shfl_xor(v2s[r], st);
            int   oi1 = __shfl_xor(i1s[r], st);
            v2s[r] = fminf(fminf(v2s[r], ov2), fmaxf(v1s[r], ov1));
            bool c = (ov1 < v1s[r]) || (ov1 == v1s[r] && oi1 < i1s[r]);
            if (c) i1s[r] = oi1;
            v1s[r] = fminf(v1s[r], ov1);
        }
    }
    if (nn == 0) {                                     // lanes 0 and 32 hold 16 rows each
        #pragma unroll
        for (int r = 0; r < 16; ++r) {
            const int row = (r & 3) + 8 * (r >> 2) + 4 * h;
            const int p = w * 32 + row;
            sv1[p] = v1s[r]; si1[p] = i1s[r]; sv2[p] = v2s[r];
        }
    }
    __syncthreads();

    // ---- flag near-ties (waves 0,1 cover points 0..127)
    {
        bool f = (tid < NPB) && ((sv2[tid] - sv1[tid]) < EPSGAP);
        ull bm = __ballot(f);
        if (lane == 0 && w < 2) msk[w] = bm;
    }
    __syncthreads();
    if (tid == 0) {
        int c = 0;
        ull m0 = msk[0];
        while (m0) { lst[1 + c++] = __ffsll(m0) - 1; m0 &= m0 - 1; }
        ull m1 = msk[1];
        while (m1) { lst[1 + c++] = 64 + (__ffsll(m1) - 1); m1 &= m1 - 1; }
        lst[0] = c;
    }
    __syncthreads();

    // ---- exact fp32 rescan, one wave per flagged point (rare: gap < 1e-3)
    const int cnt = lst[0];
    const float4* e4 = (const float4*)emb;
    for (int it = w; it < cnt; it += 4) {
        const int p = lst[1 + it];
        float xv = xbase[lane * HW + p];               // lane d holds x_d (exact fp32)
        float bv = 1e30f; int bk = 0;
        #pragma unroll
        for (int half = 0; half < 2; ++half) {
            float dacc[8];
            #pragma unroll
            for (int j = 0; j < 8; ++j) dacc[j] = 0.f;
            for (int d4 = 0; d4 < 16; ++d4) {
                float x0 = __shfl(xv, d4 * 4 + 0), x1 = __shfl(xv, d4 * 4 + 1);
                float x2 = __shfl(xv, d4 * 4 + 2), x3 = __shfl(xv, d4 * 4 + 3);
                #pragma unroll
                for (int j = 0; j < 8; ++j) {
                    const int k = lane + 64 * (half * 8 + j);
                    float4 e = e4[k * 16 + d4];
                    dacc[j] = fmaf(x0, e.x, dacc[j]); dacc[j] = fmaf(x1, e.y, dacc[j]);
                    dacc[j] = fmaf(x2, e.z, dacc[j]); dacc[j] = fmaf(x3, e.w, dacc[j]);
                }
            }
            #pragma unroll
            for (int j = 0; j < 8; ++j) {              // ascending k per lane: first-min kept
                const int k = lane + 64 * (half * 8 + j);
                float v = hsqw[k] - dacc[j];
                if (v < bv) { bv = v; bk = k; }
            }
        }
        #pragma unroll
        for (int st = 32; st; st >>= 1) {              // 64-wide (v, k) argmin, k tie-break
            float ov = __shfl_xor(bv, st);
            int   ok = __shfl_xor(bk, st);
            if (ov < bv || (ov == bv && ok < bk)) { bv = ov; bk = ok; }
        }
        if (lane == 0) si1[p] = bk;
    }
    __syncthreads();

    // ---- final: indices, quantized gather-write, loss — all 256 threads (32 dims each)
    {
        const int p = tid & 127, dg = tid >> 7;
        const int bi = si1[p];
        if (dg == 0) out[IOFF + n0 + p] = (float)bi;
        const float* e = emb + (size_t)bi * DIMS;
        const float* xp = xbase + p;
        float* oq = out + QOFF + (size_t)b * (DIMS * HW) + off + p;
        float ls = 0.f;
        #pragma unroll
        for (int d0 = 0; d0 < 32; ++d0) {
            const int d = dg * 32 + d0;
            float ev = e[d];
            float xv = xp[d * HW];
            float df = ev - xv;
            ls = fmaf(df, df, ls);
            oq[d * HW] = ev;                           // coalesced across point-threads
        }
        #pragma unroll
        for (int st = 32; st; st >>= 1) ls += __shfl_down(ls, st);
        if (lane == 0) lred[w] = ls;
    }
    __syncthreads();
    if (tid == 0) {
        float s = lred[0] + lred[1] + lred[2] + lred[3];
        atomicAdd(out, s * (0.25f / (float)(NPTS * DIMS)));
    }
}

extern "C" void kernel_launch(void* const* d_in, const int* in_sizes, int n_in,
                              void* d_out, int out_size, void* d_ws, size_t ws_size,
                              hipStream_t stream) {
    const float* in  = (const float*)d_in[0];
    const float* emb = (const float*)d_in[1];
    float* out = (float*)d_out;
    ushort* Eh  = (ushort*)d_ws;                       // 131072 B (tiled fragment order)
    ushort* El  = (ushort*)((char*)d_ws + 131072);     // 131072 B
    float*  hsq = (float*)((char*)d_ws + 262144);      // 4096 B
    (void)in_sizes; (void)n_in; (void)out_size; (void)ws_size;

    vq_prep<<<64, 256, 0, stream>>>(emb, Eh, El, hsq, out);   // also zeroes out[0]
    vq_main<<<NPTS / NPB, 256, 0, stream>>>(in, emb, Eh, El, hsq, out);
}

// Round 10
// 223.130 us; speedup vs baseline: 1.6261x; 1.6261x over previous
//
#include <hip/hip_runtime.h>

// VQ-VAE vector quantizer, R27: R24 + register-neutral deltas only (paired phases +
// setprio). R26 decomposition: the a3 chain (+16 AGPR) was the spiller — R24 sits at
// the unified-file cliff (~128 arch VGPR + ~64 AGPR = 2 waves/SIMD), so ONLY zero-
// register changes are admissible. R27 keeps computeG bit-identical to R24 (a1 4-deep
// + a2 8-deep) and adds: (1) 16 barriers instead of 32 (2 groups/phase, strictly
// sequential via sched_barrier(0) — single-group live state); (2) s_setprio(1/0)
// around the MFMA cluster (T5: 2 blocks/SIMD at independent phases).
// Structure: R18 geometry, B staged via global_load_lds(16B) into LDS ring-8 in
// MFMA-fragment order (prep pre-tiles), counted vmcnt(12) + raw s_barrier per phase
// (6 VMEM/wave/phase, distance 2 phases), A-preamble drained by vmcnt(0).
// Exactness: streaming top-2, strict-< lowest-idx, near-ties (<1e-3) fp32 rescan.
// out (fp32 concat): [ loss(1) | quantized NCHW (4194304) | indices as float (65536) ]

#define DIMS   64
#define HW     4096
#define NPTS   65536
#define NCODES 1024
#define NPB    128
#define QOFF   1
#define IOFF   (1 + NPTS * DIMS)
#define EPSGAP 1.0e-3f

typedef unsigned int uint;
typedef unsigned short ushort;
typedef unsigned long long ull;
typedef __attribute__((ext_vector_type(8))) short short8;
typedef __attribute__((ext_vector_type(16))) float f32x16;

__device__ __forceinline__ ushort bf16_rne(float f) {
    uint u = __float_as_uint(f);
    uint r = u + 0x7FFFu + ((u >> 16) & 1u);
    return (ushort)(r >> 16);
}
__device__ __forceinline__ float bf16f(ushort h) { return __uint_as_float(((uint)h) << 16); }

__device__ __forceinline__ void gload16(const void* g, void* l) {
    __builtin_amdgcn_global_load_lds(
        (const __attribute__((address_space(1))) void*)g,
        (__attribute__((address_space(3))) void*)l, 16, 0, 0);
}

// ---- prep: emb fp32 -> tiled {Eh, El} in MFMA-fragment order + hsq = 0.5||e||^2.
// Element (code c, dim d) -> ushort index g*2048 + ks*512 + (hh*32 + (c&31))*8 + (d&7),
// where g=c>>5, ks=d>>4, hh=(d>>3)&1. Lane l of group g then reads its fragment at
// [g][ks*512 + l*8] — linear in lane, so global_load_lds staging needs no swizzle.
__global__ void vq_prep(const float* __restrict__ emb, ushort* __restrict__ Eh,
                        ushort* __restrict__ El, float* __restrict__ hsq,
                        float* __restrict__ out)
{
    const int t = blockIdx.x * 256 + threadIdx.x;      // 0..16383 = code*16 + dim-group
    if (t == 0) out[0] = 0.f;
    float4 v = ((const float4*)emb)[t];
    ushort h0 = bf16_rne(v.x), h1 = bf16_rne(v.y), h2 = bf16_rne(v.z), h3 = bf16_rne(v.w);
    ushort l0 = bf16_rne(v.x - bf16f(h0)), l1 = bf16_rne(v.y - bf16f(h1));
    ushort l2 = bf16_rne(v.z - bf16f(h2)), l3 = bf16_rne(v.w - bf16f(h3));
    uint2 hp, lp;
    hp.x = (uint)h0 | ((uint)h1 << 16); hp.y = (uint)h2 | ((uint)h3 << 16);
    lp.x = (uint)l0 | ((uint)l1 << 16); lp.y = (uint)l2 | ((uint)l3 << 16);
    const int c = t >> 4, q = t & 15;
    const int g = c >> 5, nn = c & 31;
    const int d0 = q * 4;
    const int ks = d0 >> 4, hh = (d0 >> 3) & 1, j0 = d0 & 7;   // j0 in {0,4}
    const int base = g * 2048 + ks * 512 + (hh * 32 + nn) * 8 + j0;
    *(uint2*)(Eh + base) = hp;
    *(uint2*)(El + base) = lp;
    // hsq: 16 consecutive lanes hold one code's 16 float4s -> xor-shuffle reduce
    float pe = fmaf(v.x, v.x, fmaf(v.y, v.y, fmaf(v.z, v.z, v.w * v.w)));
    pe += __shfl_xor(pe, 1); pe += __shfl_xor(pe, 2);
    pe += __shfl_xor(pe, 4); pe += __shfl_xor(pe, 8);
    if ((t & 15) == 0) hsq[t >> 4] = 0.5f * pe;
}

__launch_bounds__(256, 2)
__global__ void vq_main(const float* __restrict__ in, const float* __restrict__ emb,
                        const ushort* __restrict__ Ehw, const ushort* __restrict__ Elw,
                        const float* __restrict__ hsqw, float* __restrict__ out)
{
    __shared__ ushort sEh[8][2048];                    // 8-slot ring, 4KB per slot
    __shared__ ushort sEl[8][2048];
    __shared__ float sv1[NPB];
    __shared__ float sv2[NPB];
    __shared__ int   si1[NPB];
    __shared__ ull   msk[2];
    __shared__ int   lst[1 + NPB];
    __shared__ float lred[4];

    const int tid = threadIdx.x;
    const int lane = tid & 63, w = tid >> 6;
    const int nn = lane & 31;                          // row (A) / col (B) within 32
    const int h  = lane >> 5;                          // k-half selector
    const int n0 = blockIdx.x * NPB;
    const int b = n0 >> 12, off = n0 & 4095;           // 128 | 4096: never crosses a batch
    const float* xbase = in + (size_t)b * (DIMS * HW) + off;

    // ---- A fragments: wave's 32 points, hi+lo bf16; k = ks*16 + 8h + j
    short8 Ah[4], Al[4];
    {
        const int p = w * 32 + nn;
        #pragma unroll
        for (int ks = 0; ks < 4; ++ks) {
            union { ushort u[8]; short8 v; } th, tl;
            #pragma unroll
            for (int j = 0; j < 8; ++j) {
                float x = xbase[(ks * 16 + h * 8 + j) * HW + p];
                ushort hh = bf16_rne(x);
                th.u[j] = hh;
                tl.u[j] = bf16_rne(x - bf16f(hh));
            }
            Ah[ks] = th.v; Al[ks] = tl.v;
        }
    }
    asm volatile("s_waitcnt vmcnt(0)" ::: "memory");   // counted region starts clean
    __builtin_amdgcn_sched_barrier(0);

    float v1s[16], v2s[16]; int i1s[16];
    #pragma unroll
    for (int r = 0; r < 16; ++r) { v1s[r] = 1e30f; v2s[r] = 1e30f; i1s[r] = 0; }

    // Phase s covers groups {2s, 2s+1} -> ring slots {(2s)&7, (2s+1)&7} (16KB/phase).
    // Wave roles: w>>1 selects group, w&1 selects table. 4 gload16 per wave per phase.
    auto stagePhase = [&](int s) {
        const int g0 = (2 * s < 32) ? 2 * s : 31;      // tail: dummy re-stage of grp 31
        const int g1 = (2 * s + 1 < 32) ? 2 * s + 1 : 31;
        const int gg = (w >> 1) ? g1 : g0;
        const int sl = (w >> 1) ? ((2 * s + 1) & 7) : ((2 * s) & 7);
        if ((w & 1) == 0) {
            const ushort* src = Ehw + (size_t)gg * 2048;
            #pragma unroll
            for (int u = 0; u < 4; ++u) gload16(src + u * 512 + lane * 8, &sEh[sl][u * 512]);
        } else {
            const ushort* src = Elw + (size_t)gg * 2048;
            #pragma unroll
            for (int u = 0; u < 4; ++u) gload16(src + u * 512 + lane * 8, &sEl[sl][u * 512]);
        }
    };

    auto computeG = [&](int g, int buf, float HA) {    // bit-identical to R24
        short8 Bh[4], Bl[4];
        #pragma unroll
        for (int ks = 0; ks < 4; ++ks) {               // lane-linear ds_read_b128 x8
            Bh[ks] = *(const short8*)&sEh[buf][ks * 512 + lane * 8];
            Bl[ks] = *(const short8*)&sEl[buf][ks * 512 + lane * 8];
        }
        f32x16 a1 = {0.f,0.f,0.f,0.f,0.f,0.f,0.f,0.f,0.f,0.f,0.f,0.f,0.f,0.f,0.f,0.f};
        f32x16 a2 = {0.f,0.f,0.f,0.f,0.f,0.f,0.f,0.f,0.f,0.f,0.f,0.f,0.f,0.f,0.f,0.f};
        __builtin_amdgcn_s_setprio(1);
        #pragma unroll
        for (int ks = 0; ks < 4; ++ks)                 // chain 1: hh (4-deep)
            a1 = __builtin_amdgcn_mfma_f32_32x32x16_bf16(Ah[ks], Bh[ks], a1, 0, 0, 0);
        #pragma unroll
        for (int ks = 0; ks < 4; ++ks)                 // chain 2a: hl
            a2 = __builtin_amdgcn_mfma_f32_32x32x16_bf16(Ah[ks], Bl[ks], a2, 0, 0, 0);
        #pragma unroll
        for (int ks = 0; ks < 4; ++ks)                 // chain 2b: lh (same acc, 8-deep)
            a2 = __builtin_amdgcn_mfma_f32_32x32x16_bf16(Al[ks], Bh[ks], a2, 0, 0, 0);
        __builtin_amdgcn_s_setprio(0);
        const int ca = g * 32 + nn;
        #pragma unroll
        for (int r = 0; r < 16; ++r) {                 // r -> point row (fixed lane->code)
            float d = HA - (a1[r] + a2[r]);
            v2s[r] = fminf(v2s[r], fmaxf(d, v1s[r]));  // exact streaming 2nd-min
            bool c2 = d < v1s[r];                      // strict: ascending g keeps lowest idx
            i1s[r] = c2 ? ca : i1s[r];
            v1s[r] = fminf(d, v1s[r]);
        }
    };

    // ---- K-loop: 16 phases x 2 sequential groups (sched_barrier(0) between: live
    // state stays single-group — R24's exact footprint, the cliff-safe one).
    // Per phase/wave: 4 gload_lds + 2 hsq = 6 VMEM (tail dummies keep count exact).
    // vmcnt(12): distance-2-phase prefetch stays in flight; phase-s data complete.
    stagePhase(0); float h0x = hsqw[0 * 32 + nn],  h0y = hsqw[1 * 32 + nn];
    stagePhase(1); float h1x = hsqw[2 * 32 + nn],  h1y = hsqw[3 * 32 + nn];
    float h2x, h2y, h3x, h3y;
    #pragma unroll 1
    for (int t = 0; t < 4; ++t) {
        const int P = 4 * t;                           // phases P..P+3 this body
        {
            const int s = P + 2;
            stagePhase(s);
            const int ga = (2 * s < 32) ? 2 * s : 31, gb = (2 * s + 1 < 32) ? 2 * s + 1 : 31;
            h2x = hsqw[ga * 32 + nn]; h2y = hsqw[gb * 32 + nn];
            asm volatile("s_waitcnt vmcnt(12)\ns_barrier" ::: "memory");
            const int g = 2 * P;
            computeG(g, g & 7, h0x);
            __builtin_amdgcn_sched_barrier(0);
            computeG(g + 1, (g + 1) & 7, h0y);
        }
        {
            const int s = P + 3;
            stagePhase(s);
            const int ga = (2 * s < 32) ? 2 * s : 31, gb = (2 * s + 1 < 32) ? 2 * s + 1 : 31;
            h3x = hsqw[ga * 32 + nn]; h3y = hsqw[gb * 32 + nn];
            asm volatile("s_waitcnt vmcnt(12)\ns_barrier" ::: "memory");
            const int g = 2 * P + 2;
            computeG(g, g & 7, h1x);
            __builtin_amdgcn_sched_barrier(0);
            computeG(g + 1, (g + 1) & 7, h1y);
        }
        {
            const int s = P + 4;
            stagePhase(s);
            const int ga = (2 * s < 32) ? 2 * s : 31, gb = (2 * s + 1 < 32) ? 2 * s + 1 : 31;
            h0x = hsqw[ga * 32 + nn]; h0y = hsqw[gb * 32 + nn];
            asm volatile("s_waitcnt vmcnt(12)\ns_barrier" ::: "memory");
            const int g = 2 * P + 4;
            computeG(g, g & 7, h2x);
            __builtin_amdgcn_sched_barrier(0);
            computeG(g + 1, (g + 1) & 7, h2y);
        }
        {
            const int s = P + 5;
            stagePhase(s);
            const int ga = (2 * s < 32) ? 2 * s : 31, gb = (2 * s + 1 < 32) ? 2 * s + 1 : 31;
            h1x = hsqw[ga * 32 + nn]; h1y = hsqw[gb * 32 + nn];
            asm volatile("s_waitcnt vmcnt(12)\ns_barrier" ::: "memory");
            const int g = 2 * P + 6;
            computeG(g, g & 7, h3x);
            __builtin_amdgcn_sched_barrier(0);
            computeG(g + 1, (g + 1) & 7, h3y);
        }
    }

    // ---- merge across the 32 code-lanes (both k-halves of a point share a half-wave)
    #pragma unroll
    for (int st = 1; st < 32; st <<= 1) {
        #pragma unroll
        for (int r = 0; r < 16; ++r) {
            float ov1 = __shfl_xor(v1s[r], st);
            float ov2 = __shfl_xor(v2s[r], st);
            int   oi1 = __shfl_xor(i1s[r], st);
            v2s[r] = fminf(fminf(v2s[r], ov2), fmaxf(v1s[r], ov1));
            bool c = (ov1 < v1s[r]) || (ov1 == v1s[r] && oi1 < i1s[r]);
            if (c) i1s[r] = oi1;
            v1s[r] = fminf(v1s[r], ov1);
        }
    }
    if (nn == 0) {                                     // lanes 0 and 32 hold 16 rows each
        #pragma unroll
        for (int r = 0; r < 16; ++r) {
            const int row = (r & 3) + 8 * (r >> 2) + 4 * h;
            const int p = w * 32 + row;
            sv1[p] = v1s[r]; si1[p] = i1s[r]; sv2[p] = v2s[r];
        }
    }
    __syncthreads();

    // ---- flag near-ties (waves 0,1 cover points 0..127)
    {
        bool f = (tid < NPB) && ((sv2[tid] - sv1[tid]) < EPSGAP);
        ull bm = __ballot(f);
        if (lane == 0 && w < 2) msk[w] = bm;
    }
    __syncthreads();
    if (tid == 0) {
        int c = 0;
        ull m0 = msk[0];
        while (m0) { lst[1 + c++] = __ffsll(m0) - 1; m0 &= m0 - 1; }
        ull m1 = msk[1];
        while (m1) { lst[1 + c++] = 64 + (__ffsll(m1) - 1); m1 &= m1 - 1; }
        lst[0] = c;
    }
    __syncthreads();

    // ---- exact fp32 rescan, one wave per flagged point (rare: gap < 1e-3)
    const int cnt = lst[0];
    const float4* e4 = (const float4*)emb;
    for (int it = w; it < cnt; it += 4) {
        const int p = lst[1 + it];
        float xv = xbase[lane * HW + p];               // lane d holds x_d (exact fp32)
        float bv = 1e30f; int bk = 0;
        #pragma unroll
        for (int half = 0; half < 2; ++half) {
            float dacc[8];
            #pragma unroll
            for (int j = 0; j < 8; ++j) dacc[j] = 0.f;
            for (int d4 = 0; d4 < 16; ++d4) {
                float x0 = __shfl(xv, d4 * 4 + 0), x1 = __shfl(xv, d4 * 4 + 1);
                float x2 = __shfl(xv, d4 * 4 + 2), x3 = __shfl(xv, d4 * 4 + 3);
                #pragma unroll
                for (int j = 0; j < 8; ++j) {
                    const int k = lane + 64 * (half * 8 + j);
                    float4 e = e4[k * 16 + d4];
                    dacc[j] = fmaf(x0, e.x, dacc[j]); dacc[j] = fmaf(x1, e.y, dacc[j]);
                    dacc[j] = fmaf(x2, e.z, dacc[j]); dacc[j] = fmaf(x3, e.w, dacc[j]);
                }
            }
            #pragma unroll
            for (int j = 0; j < 8; ++j) {              // ascending k per lane: first-min kept
                const int k = lane + 64 * (half * 8 + j);
                float v = hsqw[k] - dacc[j];
                if (v < bv) { bv = v; bk = k; }
            }
        }
        #pragma unroll
        for (int st = 32; st; st >>= 1) {              // 64-wide (v, k) argmin, k tie-break
            float ov = __shfl_xor(bv, st);
            int   ok = __shfl_xor(bk, st);
            if (ov < bv || (ov == bv && ok < bk)) { bv = ov; bk = ok; }
        }
        if (lane == 0) si1[p] = bk;
    }
    __syncthreads();

    // ---- final: indices, quantized gather-write, loss — all 256 threads (32 dims each)
    {
        const int p = tid & 127, dg = tid >> 7;
        const int bi = si1[p];
        if (dg == 0) out[IOFF + n0 + p] = (float)bi;
        const float* e = emb + (size_t)bi * DIMS;
        const float* xp = xbase + p;
        float* oq = out + QOFF + (size_t)b * (DIMS * HW) + off + p;
        float ls = 0.f;
        #pragma unroll
        for (int d0 = 0; d0 < 32; ++d0) {
            const int d = dg * 32 + d0;
            float ev = e[d];
            float xv = xp[d * HW];
            float df = ev - xv;
            ls = fmaf(df, df, ls);
            oq[d * HW] = ev;                           // coalesced across point-threads
        }
        #pragma unroll
        for (int st = 32; st; st >>= 1) ls += __shfl_down(ls, st);
        if (lane == 0) lred[w] = ls;
    }
    __syncthreads();
    if (tid == 0) {
        float s = lred[0] + lred[1] + lred[2] + lred[3];
        atomicAdd(out, s * (0.25f / (float)(NPTS * DIMS)));
    }
}

extern "C" void kernel_launch(void* const* d_in, const int* in_sizes, int n_in,
                              void* d_out, int out_size, void* d_ws, size_t ws_size,
                              hipStream_t stream) {
    const float* in  = (const float*)d_in[0];
    const float* emb = (const float*)d_in[1];
    float* out = (float*)d_out;
    ushort* Eh  = (ushort*)d_ws;                       // 131072 B (tiled fragment order)
    ushort* El  = (ushort*)((char*)d_ws + 131072);     // 131072 B
    float*  hsq = (float*)((char*)d_ws + 262144);      // 4096 B
    (void)in_sizes; (void)n_in; (void)out_size; (void)ws_size;

    vq_prep<<<64, 256, 0, stream>>>(emb, Eh, El, hsq, out);   // also zeroes out[0]
    vq_main<<<NPTS / NPB, 256, 0, stream>>>(in, emb, Eh, El, hsq, out);
}

// Round 11
// 125.672 us; speedup vs baseline: 2.8871x; 1.7755x over previous
//
#include <hip/hip_runtime.h>

// VQ-VAE vector quantizer, R28: R24 byte-identical + s_setprio(1/0) around the MFMA
// cluster — the ONLY untested zero-register delta.
// Session law (R24-R27): loop body with 4 inlined computeG = clean alloc at the
// 192-reg unified-file cliff (128 arch + 64 AGPR, 2 waves/SIMD); 8 instances = spill
// regardless of sched_barrier fencing (R25 309MB, R26 641MB, R27 386MB scratch).
// Pairing/deepening/thinning all dead ends; R24 (63.0us kernel / 123.8us bench) is
// the structure's optimum. T5 applies here (2 blocks/SIMD at independent phases =
// role diversity, the attn-like +4-7% case, not the lockstep-GEMM null).
// Structure: R18 geometry, B staged via global_load_lds(16B) into LDS ring-8 in
// MFMA-fragment order (prep pre-tiles), counted vmcnt(6) + raw s_barrier per group,
// 3 VMEM/wave/group, prefetch distance 3, A-preamble outside the counted region.
// Exactness: streaming top-2, strict-< lowest-idx, near-ties (<1e-3) fp32 rescan.
// out (fp32 concat): [ loss(1) | quantized NCHW (4194304) | indices as float (65536) ]

#define DIMS   64
#define HW     4096
#define NPTS   65536
#define NCODES 1024
#define NPB    128
#define QOFF   1
#define IOFF   (1 + NPTS * DIMS)
#define EPSGAP 1.0e-3f

typedef unsigned int uint;
typedef unsigned short ushort;
typedef unsigned long long ull;
typedef __attribute__((ext_vector_type(8))) short short8;
typedef __attribute__((ext_vector_type(16))) float f32x16;

__device__ __forceinline__ ushort bf16_rne(float f) {
    uint u = __float_as_uint(f);
    uint r = u + 0x7FFFu + ((u >> 16) & 1u);
    return (ushort)(r >> 16);
}
__device__ __forceinline__ float bf16f(ushort h) { return __uint_as_float(((uint)h) << 16); }

__device__ __forceinline__ void gload16(const void* g, void* l) {
    __builtin_amdgcn_global_load_lds(
        (const __attribute__((address_space(1))) void*)g,
        (__attribute__((address_space(3))) void*)l, 16, 0, 0);
}

// ---- prep: emb fp32 -> tiled {Eh, El} in MFMA-fragment order + hsq = 0.5||e||^2.
// Element (code c, dim d) -> ushort index g*2048 + ks*512 + (hh*32 + (c&31))*8 + (d&7),
// where g=c>>5, ks=d>>4, hh=(d>>3)&1. Lane l of group g then reads its fragment at
// [g][ks*512 + l*8] — linear in lane, so global_load_lds staging needs no swizzle.
__global__ void vq_prep(const float* __restrict__ emb, ushort* __restrict__ Eh,
                        ushort* __restrict__ El, float* __restrict__ hsq,
                        float* __restrict__ out)
{
    const int t = blockIdx.x * 256 + threadIdx.x;      // 0..16383 = code*16 + dim-group
    if (t == 0) out[0] = 0.f;
    float4 v = ((const float4*)emb)[t];
    ushort h0 = bf16_rne(v.x), h1 = bf16_rne(v.y), h2 = bf16_rne(v.z), h3 = bf16_rne(v.w);
    ushort l0 = bf16_rne(v.x - bf16f(h0)), l1 = bf16_rne(v.y - bf16f(h1));
    ushort l2 = bf16_rne(v.z - bf16f(h2)), l3 = bf16_rne(v.w - bf16f(h3));
    uint2 hp, lp;
    hp.x = (uint)h0 | ((uint)h1 << 16); hp.y = (uint)h2 | ((uint)h3 << 16);
    lp.x = (uint)l0 | ((uint)l1 << 16); lp.y = (uint)l2 | ((uint)l3 << 16);
    const int c = t >> 4, q = t & 15;
    const int g = c >> 5, nn = c & 31;
    const int d0 = q * 4;
    const int ks = d0 >> 4, hh = (d0 >> 3) & 1, j0 = d0 & 7;   // j0 in {0,4}
    const int base = g * 2048 + ks * 512 + (hh * 32 + nn) * 8 + j0;
    *(uint2*)(Eh + base) = hp;
    *(uint2*)(El + base) = lp;
    // hsq: 16 consecutive lanes hold one code's 16 float4s -> xor-shuffle reduce
    float pe = fmaf(v.x, v.x, fmaf(v.y, v.y, fmaf(v.z, v.z, v.w * v.w)));
    pe += __shfl_xor(pe, 1); pe += __shfl_xor(pe, 2);
    pe += __shfl_xor(pe, 4); pe += __shfl_xor(pe, 8);
    if ((t & 15) == 0) hsq[t >> 4] = 0.5f * pe;
}

__launch_bounds__(256, 2)
__global__ void vq_main(const float* __restrict__ in, const float* __restrict__ emb,
                        const ushort* __restrict__ Ehw, const ushort* __restrict__ Elw,
                        const float* __restrict__ hsqw, float* __restrict__ out)
{
    __shared__ ushort sEh[8][2048];                    // 8-slot ring, 4KB per slot
    __shared__ ushort sEl[8][2048];
    __shared__ float sv1[NPB];
    __shared__ float sv2[NPB];
    __shared__ int   si1[NPB];
    __shared__ ull   msk[2];
    __shared__ int   lst[1 + NPB];
    __shared__ float lred[4];

    const int tid = threadIdx.x;
    const int lane = tid & 63, w = tid >> 6;
    const int nn = lane & 31;                          // row (A) / col (B) within 32
    const int h  = lane >> 5;                          // k-half selector
    const int n0 = blockIdx.x * NPB;
    const int b = n0 >> 12, off = n0 & 4095;           // 128 | 4096: never crosses a batch
    const float* xbase = in + (size_t)b * (DIMS * HW) + off;

    // ---- A fragments: wave's 32 points, hi+lo bf16; k = ks*16 + 8h + j
    short8 Ah[4], Al[4];
    {
        const int p = w * 32 + nn;
        #pragma unroll
        for (int ks = 0; ks < 4; ++ks) {
            union { ushort u[8]; short8 v; } th, tl;
            #pragma unroll
            for (int j = 0; j < 8; ++j) {
                float x = xbase[(ks * 16 + h * 8 + j) * HW + p];
                ushort hh = bf16_rne(x);
                th.u[j] = hh;
                tl.u[j] = bf16_rne(x - bf16f(hh));
            }
            Ah[ks] = th.v; Al[ks] = tl.v;
        }
    }
    asm volatile("s_waitcnt vmcnt(0)" ::: "memory");   // counted region starts clean
    __builtin_amdgcn_sched_barrier(0);

    float v1s[16], v2s[16]; int i1s[16];
    #pragma unroll
    for (int r = 0; r < 16; ++r) { v1s[r] = 1e30f; v2s[r] = 1e30f; i1s[r] = 0; }

    // wave w stages chunks {2w, 2w+1} of the group's 8KB (i<4 -> Eh, else El): exactly
    // 2 global_load_lds per wave per group — the vmcnt(6) count relies on this.
    auto stage = [&](int sg, int buf) {
        #pragma unroll
        for (int u = 0; u < 2; ++u) {
            const int i = 2 * w + u;
            const int c4 = (i & 3) * 512;
            if (i < 4) gload16(Ehw + (size_t)sg * 2048 + c4 + lane * 8, &sEh[buf][c4]);
            else       gload16(Elw + (size_t)sg * 2048 + c4 + lane * 8, &sEl[buf][c4]);
        }
    };

    auto computeG = [&](int g, int buf, float HA) {
        short8 Bh[4], Bl[4];
        #pragma unroll
        for (int ks = 0; ks < 4; ++ks) {               // lane-linear ds_read_b128 x8
            Bh[ks] = *(const short8*)&sEh[buf][ks * 512 + lane * 8];
            Bl[ks] = *(const short8*)&sEl[buf][ks * 512 + lane * 8];
        }
        f32x16 a1 = {0.f,0.f,0.f,0.f,0.f,0.f,0.f,0.f,0.f,0.f,0.f,0.f,0.f,0.f,0.f,0.f};
        f32x16 a2 = {0.f,0.f,0.f,0.f,0.f,0.f,0.f,0.f,0.f,0.f,0.f,0.f,0.f,0.f,0.f,0.f};
        __builtin_amdgcn_s_setprio(1);
        #pragma unroll
        for (int ks = 0; ks < 4; ++ks)                 // chain 1: hh (4-deep)
            a1 = __builtin_amdgcn_mfma_f32_32x32x16_bf16(Ah[ks], Bh[ks], a1, 0, 0, 0);
        #pragma unroll
        for (int ks = 0; ks < 4; ++ks)                 // chain 2a: hl
            a2 = __builtin_amdgcn_mfma_f32_32x32x16_bf16(Ah[ks], Bl[ks], a2, 0, 0, 0);
        #pragma unroll
        for (int ks = 0; ks < 4; ++ks)                 // chain 2b: lh (same acc, 8-deep)
            a2 = __builtin_amdgcn_mfma_f32_32x32x16_bf16(Al[ks], Bh[ks], a2, 0, 0, 0);
        __builtin_amdgcn_s_setprio(0);
        const int ca = g * 32 + nn;
        #pragma unroll
        for (int r = 0; r < 16; ++r) {                 // r -> point row (fixed lane->code)
            float d = HA - (a1[r] + a2[r]);
            v2s[r] = fminf(v2s[r], fmaxf(d, v1s[r]));  // exact streaming 2nd-min
            bool c2 = d < v1s[r];                      // strict: ascending g keeps lowest idx
            i1s[r] = c2 ? ca : i1s[r];
            v1s[r] = fminf(d, v1s[r]);
        }
    };

    // ---- K-loop: 32 groups of 32 codes; LDS ring-8, prefetch distance 3.
    // Per iter/wave: 2 stages + 1 hsq = 3 VMEM (tail dummy-clamped to keep count exact).
    // vmcnt(6) + raw s_barrier in ONE asm: group-g data complete, no full drain.
    stage(0, 0); float hqA = hsqw[nn];
    stage(1, 1); float hqB = hsqw[32 + nn];
    stage(2, 2); float hqC = hsqw[64 + nn];
    float hqD;
    #pragma unroll 1
    for (int g = 0; g < 32; g += 4) {
        {
            const int s = g + 3;                       // <=31 always
            stage(s, (g + 3) & 7); hqD = hsqw[s * 32 + nn];
            asm volatile("s_waitcnt vmcnt(6)\ns_barrier" ::: "memory");
            computeG(g, g & 7, hqA);
        }
        {
            const int s = (g + 4 < 32) ? g + 4 : 31;
            stage(s, (g + 4) & 7); hqA = hsqw[s * 32 + nn];
            asm volatile("s_waitcnt vmcnt(6)\ns_barrier" ::: "memory");
            computeG(g + 1, (g + 1) & 7, hqB);
        }
        {
            const int s = (g + 5 < 32) ? g + 5 : 31;
            stage(s, (g + 5) & 7); hqB = hsqw[s * 32 + nn];
            asm volatile("s_waitcnt vmcnt(6)\ns_barrier" ::: "memory");
            computeG(g + 2, (g + 2) & 7, hqC);
        }
        {
            const int s = (g + 6 < 32) ? g + 6 : 31;
            stage(s, (g + 6) & 7); hqC = hsqw[s * 32 + nn];
            asm volatile("s_waitcnt vmcnt(6)\ns_barrier" ::: "memory");
            computeG(g + 3, (g + 3) & 7, hqD);
        }
    }

    // ---- merge across the 32 code-lanes (both k-halves of a point share a half-wave)
    #pragma unroll
    for (int st = 1; st < 32; st <<= 1) {
        #pragma unroll
        for (int r = 0; r < 16; ++r) {
            float ov1 = __shfl_xor(v1s[r], st);
            float ov2 = __shfl_xor(v2s[r], st);
            int   oi1 = __shfl_xor(i1s[r], st);
            v2s[r] = fminf(fminf(v2s[r], ov2), fmaxf(v1s[r], ov1));
            bool c = (ov1 < v1s[r]) || (ov1 == v1s[r] && oi1 < i1s[r]);
            if (c) i1s[r] = oi1;
            v1s[r] = fminf(v1s[r], ov1);
        }
    }
    if (nn == 0) {                                     // lanes 0 and 32 hold 16 rows each
        #pragma unroll
        for (int r = 0; r < 16; ++r) {
            const int row = (r & 3) + 8 * (r >> 2) + 4 * h;
            const int p = w * 32 + row;
            sv1[p] = v1s[r]; si1[p] = i1s[r]; sv2[p] = v2s[r];
        }
    }
    __syncthreads();

    // ---- flag near-ties (waves 0,1 cover points 0..127)
    {
        bool f = (tid < NPB) && ((sv2[tid] - sv1[tid]) < EPSGAP);
        ull bm = __ballot(f);
        if (lane == 0 && w < 2) msk[w] = bm;
    }
    __syncthreads();
    if (tid == 0) {
        int c = 0;
        ull m0 = msk[0];
        while (m0) { lst[1 + c++] = __ffsll(m0) - 1; m0 &= m0 - 1; }
        ull m1 = msk[1];
        while (m1) { lst[1 + c++] = 64 + (__ffsll(m1) - 1); m1 &= m1 - 1; }
        lst[0] = c;
    }
    __syncthreads();

    // ---- exact fp32 rescan, one wave per flagged point (rare: gap < 1e-3)
    const int cnt = lst[0];
    const float4* e4 = (const float4*)emb;
    for (int it = w; it < cnt; it += 4) {
        const int p = lst[1 + it];
        float xv = xbase[lane * HW + p];               // lane d holds x_d (exact fp32)
        float bv = 1e30f; int bk = 0;
        #pragma unroll
        for (int half = 0; half < 2; ++half) {
            float dacc[8];
            #pragma unroll
            for (int j = 0; j < 8; ++j) dacc[j] = 0.f;
            for (int d4 = 0; d4 < 16; ++d4) {
                float x0 = __shfl(xv, d4 * 4 + 0), x1 = __shfl(xv, d4 * 4 + 1);
                float x2 = __shfl(xv, d4 * 4 + 2), x3 = __shfl(xv, d4 * 4 + 3);
                #pragma unroll
                for (int j = 0; j < 8; ++j) {
                    const int k = lane + 64 * (half * 8 + j);
                    float4 e = e4[k * 16 + d4];
                    dacc[j] = fmaf(x0, e.x, dacc[j]); dacc[j] = fmaf(x1, e.y, dacc[j]);
                    dacc[j] = fmaf(x2, e.z, dacc[j]); dacc[j] = fmaf(x3, e.w, dacc[j]);
                }
            }
            #pragma unroll
            for (int j = 0; j < 8; ++j) {              // ascending k per lane: first-min kept
                const int k = lane + 64 * (half * 8 + j);
                float v = hsqw[k] - dacc[j];
                if (v < bv) { bv = v; bk = k; }
            }
        }
        #pragma unroll
        for (int st = 32; st; st >>= 1) {              // 64-wide (v, k) argmin, k tie-break
            float ov = __shfl_xor(bv, st);
            int   ok = __shfl_xor(bk, st);
            if (ov < bv || (ov == bv && ok < bk)) { bv = ov; bk = ok; }
        }
        if (lane == 0) si1[p] = bk;
    }
    __syncthreads();

    // ---- final: indices, quantized gather-write, loss — all 256 threads (32 dims each)
    {
        const int p = tid & 127, dg = tid >> 7;
        const int bi = si1[p];
        if (dg == 0) out[IOFF + n0 + p] = (float)bi;
        const float* e = emb + (size_t)bi * DIMS;
        const float* xp = xbase + p;
        float* oq = out + QOFF + (size_t)b * (DIMS * HW) + off + p;
        float ls = 0.f;
        #pragma unroll
        for (int d0 = 0; d0 < 32; ++d0) {
            const int d = dg * 32 + d0;
            float ev = e[d];
            float xv = xp[d * HW];
            float df = ev - xv;
            ls = fmaf(df, df, ls);
            oq[d * HW] = ev;                           // coalesced across point-threads
        }
        #pragma unroll
        for (int st = 32; st; st >>= 1) ls += __shfl_down(ls, st);
        if (lane == 0) lred[w] = ls;
    }
    __syncthreads();
    if (tid == 0) {
        float s = lred[0] + lred[1] + lred[2] + lred[3];
        atomicAdd(out, s * (0.25f / (float)(NPTS * DIMS)));
    }
}

extern "C" void kernel_launch(void* const* d_in, const int* in_sizes, int n_in,
                              void* d_out, int out_size, void* d_ws, size_t ws_size,
                              hipStream_t stream) {
    const float* in  = (const float*)d_in[0];
    const float* emb = (const float*)d_in[1];
    float* out = (float*)d_out;
    ushort* Eh  = (ushort*)d_ws;                       // 131072 B (tiled fragment order)
    ushort* El  = (ushort*)((char*)d_ws + 131072);     // 131072 B
    float*  hsq = (float*)((char*)d_ws + 262144);      // 4096 B
    (void)in_sizes; (void)n_in; (void)out_size; (void)ws_size;

    vq_prep<<<64, 256, 0, stream>>>(emb, Eh, El, hsq, out);   // also zeroes out[0]
    vq_main<<<NPTS / NPB, 256, 0, stream>>>(in, emb, Eh, El, hsq, out);
}

// Round 12
// 124.330 us; speedup vs baseline: 2.9182x; 1.0108x over previous
//
#include <hip/hip_runtime.h>

// VQ-VAE vector quantizer, FINAL (R29 = R24, session best: 63.0us kernel / 123.8us
// bench, from 153.3us baseline). Setprio (R28) reverted: measured null-to-negative
// (125.7 vs 123.8), consistent with T5's lockstep-null case.
// Session model (R18-R28, all measured):
//  - Register cliff: per-wave state ~192 unified regs (A 32 + B 32 + top-2 48 +
//    accum 32 AGPR + addr) -> 2 waves/SIMD. <=128 needs dropping the exact-top-2 /
//    split-bf16 state; the thin version that fits (R21) loses 2.3x to exposed latency.
//  - Allocator law: 4 inlined computeG per loop body = clean alloc; 8 = 300-640MB
//    scratch spill regardless of sched_barrier fencing (R25/R26/R27).
//  - Pipeline: LDS ring-8 + counted vmcnt(6) distance-3 is sufficient (R24 -35% vs
//    R18); deeper spills (R22), shallower stalls (R23), occupancy pushes all lose
//    more in pipeline quality than they gain (R19-R23).
// Structure: B staged via global_load_lds(16B) into 8-slot LDS ring in MFMA-fragment
// order (prep pre-tiles: staging is lane-linear AND ds_read_b128 is conflict-free),
// counted s_waitcnt vmcnt(6) + raw s_barrier per group (never a full drain),
// 3 VMEM/wave/group exact (tail dummy-clamped), A-preamble drained by vmcnt(0).
// Math: 32x32x16 MFMA, dot = xh.eh + xh.el + xl.eh (a1 4-deep, a2 8-deep), exact
// streaming top-2, strict-< lowest-idx tie-break, near-ties (<1e-3) fp32 rescan.
// out (fp32 concat): [ loss(1) | quantized NCHW (4194304) | indices as float (65536) ]

#define DIMS   64
#define HW     4096
#define NPTS   65536
#define NCODES 1024
#define NPB    128
#define QOFF   1
#define IOFF   (1 + NPTS * DIMS)
#define EPSGAP 1.0e-3f

typedef unsigned int uint;
typedef unsigned short ushort;
typedef unsigned long long ull;
typedef __attribute__((ext_vector_type(8))) short short8;
typedef __attribute__((ext_vector_type(16))) float f32x16;

__device__ __forceinline__ ushort bf16_rne(float f) {
    uint u = __float_as_uint(f);
    uint r = u + 0x7FFFu + ((u >> 16) & 1u);
    return (ushort)(r >> 16);
}
__device__ __forceinline__ float bf16f(ushort h) { return __uint_as_float(((uint)h) << 16); }

__device__ __forceinline__ void gload16(const void* g, void* l) {
    __builtin_amdgcn_global_load_lds(
        (const __attribute__((address_space(1))) void*)g,
        (__attribute__((address_space(3))) void*)l, 16, 0, 0);
}

// ---- prep: emb fp32 -> tiled {Eh, El} in MFMA-fragment order + hsq = 0.5||e||^2.
// Element (code c, dim d) -> ushort index g*2048 + ks*512 + (hh*32 + (c&31))*8 + (d&7),
// where g=c>>5, ks=d>>4, hh=(d>>3)&1. Lane l of group g then reads its fragment at
// [g][ks*512 + l*8] — linear in lane, so global_load_lds staging needs no swizzle.
__global__ void vq_prep(const float* __restrict__ emb, ushort* __restrict__ Eh,
                        ushort* __restrict__ El, float* __restrict__ hsq,
                        float* __restrict__ out)
{
    const int t = blockIdx.x * 256 + threadIdx.x;      // 0..16383 = code*16 + dim-group
    if (t == 0) out[0] = 0.f;
    float4 v = ((const float4*)emb)[t];
    ushort h0 = bf16_rne(v.x), h1 = bf16_rne(v.y), h2 = bf16_rne(v.z), h3 = bf16_rne(v.w);
    ushort l0 = bf16_rne(v.x - bf16f(h0)), l1 = bf16_rne(v.y - bf16f(h1));
    ushort l2 = bf16_rne(v.z - bf16f(h2)), l3 = bf16_rne(v.w - bf16f(h3));
    uint2 hp, lp;
    hp.x = (uint)h0 | ((uint)h1 << 16); hp.y = (uint)h2 | ((uint)h3 << 16);
    lp.x = (uint)l0 | ((uint)l1 << 16); lp.y = (uint)l2 | ((uint)l3 << 16);
    const int c = t >> 4, q = t & 15;
    const int g = c >> 5, nn = c & 31;
    const int d0 = q * 4;
    const int ks = d0 >> 4, hh = (d0 >> 3) & 1, j0 = d0 & 7;   // j0 in {0,4}
    const int base = g * 2048 + ks * 512 + (hh * 32 + nn) * 8 + j0;
    *(uint2*)(Eh + base) = hp;
    *(uint2*)(El + base) = lp;
    // hsq: 16 consecutive lanes hold one code's 16 float4s -> xor-shuffle reduce
    float pe = fmaf(v.x, v.x, fmaf(v.y, v.y, fmaf(v.z, v.z, v.w * v.w)));
    pe += __shfl_xor(pe, 1); pe += __shfl_xor(pe, 2);
    pe += __shfl_xor(pe, 4); pe += __shfl_xor(pe, 8);
    if ((t & 15) == 0) hsq[t >> 4] = 0.5f * pe;
}

__launch_bounds__(256, 2)
__global__ void vq_main(const float* __restrict__ in, const float* __restrict__ emb,
                        const ushort* __restrict__ Ehw, const ushort* __restrict__ Elw,
                        const float* __restrict__ hsqw, float* __restrict__ out)
{
    __shared__ ushort sEh[8][2048];                    // 8-slot ring, 4KB per slot
    __shared__ ushort sEl[8][2048];
    __shared__ float sv1[NPB];
    __shared__ float sv2[NPB];
    __shared__ int   si1[NPB];
    __shared__ ull   msk[2];
    __shared__ int   lst[1 + NPB];
    __shared__ float lred[4];

    const int tid = threadIdx.x;
    const int lane = tid & 63, w = tid >> 6;
    const int nn = lane & 31;                          // row (A) / col (B) within 32
    const int h  = lane >> 5;                          // k-half selector
    const int n0 = blockIdx.x * NPB;
    const int b = n0 >> 12, off = n0 & 4095;           // 128 | 4096: never crosses a batch
    const float* xbase = in + (size_t)b * (DIMS * HW) + off;

    // ---- A fragments: wave's 32 points, hi+lo bf16; k = ks*16 + 8h + j
    short8 Ah[4], Al[4];
    {
        const int p = w * 32 + nn;
        #pragma unroll
        for (int ks = 0; ks < 4; ++ks) {
            union { ushort u[8]; short8 v; } th, tl;
            #pragma unroll
            for (int j = 0; j < 8; ++j) {
                float x = xbase[(ks * 16 + h * 8 + j) * HW + p];
                ushort hh = bf16_rne(x);
                th.u[j] = hh;
                tl.u[j] = bf16_rne(x - bf16f(hh));
            }
            Ah[ks] = th.v; Al[ks] = tl.v;
        }
    }
    asm volatile("s_waitcnt vmcnt(0)" ::: "memory");   // counted region starts clean
    __builtin_amdgcn_sched_barrier(0);

    float v1s[16], v2s[16]; int i1s[16];
    #pragma unroll
    for (int r = 0; r < 16; ++r) { v1s[r] = 1e30f; v2s[r] = 1e30f; i1s[r] = 0; }

    // wave w stages chunks {2w, 2w+1} of the group's 8KB (i<4 -> Eh, else El): exactly
    // 2 global_load_lds per wave per group — the vmcnt(6) count relies on this.
    auto stage = [&](int sg, int buf) {
        #pragma unroll
        for (int u = 0; u < 2; ++u) {
            const int i = 2 * w + u;
            const int c4 = (i & 3) * 512;
            if (i < 4) gload16(Ehw + (size_t)sg * 2048 + c4 + lane * 8, &sEh[buf][c4]);
            else       gload16(Elw + (size_t)sg * 2048 + c4 + lane * 8, &sEl[buf][c4]);
        }
    };

    auto computeG = [&](int g, int buf, float HA) {
        short8 Bh[4], Bl[4];
        #pragma unroll
        for (int ks = 0; ks < 4; ++ks) {               // lane-linear ds_read_b128 x8
            Bh[ks] = *(const short8*)&sEh[buf][ks * 512 + lane * 8];
            Bl[ks] = *(const short8*)&sEl[buf][ks * 512 + lane * 8];
        }
        f32x16 a1 = {0.f,0.f,0.f,0.f,0.f,0.f,0.f,0.f,0.f,0.f,0.f,0.f,0.f,0.f,0.f,0.f};
        f32x16 a2 = {0.f,0.f,0.f,0.f,0.f,0.f,0.f,0.f,0.f,0.f,0.f,0.f,0.f,0.f,0.f,0.f};
        #pragma unroll
        for (int ks = 0; ks < 4; ++ks)                 // chain 1: hh (4-deep)
            a1 = __builtin_amdgcn_mfma_f32_32x32x16_bf16(Ah[ks], Bh[ks], a1, 0, 0, 0);
        #pragma unroll
        for (int ks = 0; ks < 4; ++ks)                 // chain 2a: hl
            a2 = __builtin_amdgcn_mfma_f32_32x32x16_bf16(Ah[ks], Bl[ks], a2, 0, 0, 0);
        #pragma unroll
        for (int ks = 0; ks < 4; ++ks)                 // chain 2b: lh (same acc, 8-deep)
            a2 = __builtin_amdgcn_mfma_f32_32x32x16_bf16(Al[ks], Bh[ks], a2, 0, 0, 0);
        const int ca = g * 32 + nn;
        #pragma unroll
        for (int r = 0; r < 16; ++r) {                 // r -> point row (fixed lane->code)
            float d = HA - (a1[r] + a2[r]);
            v2s[r] = fminf(v2s[r], fmaxf(d, v1s[r]));  // exact streaming 2nd-min
            bool c2 = d < v1s[r];                      // strict: ascending g keeps lowest idx
            i1s[r] = c2 ? ca : i1s[r];
            v1s[r] = fminf(d, v1s[r]);
        }
    };

    // ---- K-loop: 32 groups of 32 codes; LDS ring-8, prefetch distance 3.
    // Per iter/wave: 2 stages + 1 hsq = 3 VMEM (tail dummy-clamped to keep count exact).
    // vmcnt(6) + raw s_barrier in ONE asm: group-g data complete, no full drain.
    stage(0, 0); float hqA = hsqw[nn];
    stage(1, 1); float hqB = hsqw[32 + nn];
    stage(2, 2); float hqC = hsqw[64 + nn];
    float hqD;
    #pragma unroll 1
    for (int g = 0; g < 32; g += 4) {
        {
            const int s = g + 3;                       // <=31 always
            stage(s, (g + 3) & 7); hqD = hsqw[s * 32 + nn];
            asm volatile("s_waitcnt vmcnt(6)\ns_barrier" ::: "memory");
            computeG(g, g & 7, hqA);
        }
        {
            const int s = (g + 4 < 32) ? g + 4 : 31;
            stage(s, (g + 4) & 7); hqA = hsqw[s * 32 + nn];
            asm volatile("s_waitcnt vmcnt(6)\ns_barrier" ::: "memory");
            computeG(g + 1, (g + 1) & 7, hqB);
        }
        {
            const int s = (g + 5 < 32) ? g + 5 : 31;
            stage(s, (g + 5) & 7); hqB = hsqw[s * 32 + nn];
            asm volatile("s_waitcnt vmcnt(6)\ns_barrier" ::: "memory");
            computeG(g + 2, (g + 2) & 7, hqC);
        }
        {
            const int s = (g + 6 < 32) ? g + 6 : 31;
            stage(s, (g + 6) & 7); hqC = hsqw[s * 32 + nn];
            asm volatile("s_waitcnt vmcnt(6)\ns_barrier" ::: "memory");
            computeG(g + 3, (g + 3) & 7, hqD);
        }
    }

    // ---- merge across the 32 code-lanes (both k-halves of a point share a half-wave)
    #pragma unroll
    for (int st = 1; st < 32; st <<= 1) {
        #pragma unroll
        for (int r = 0; r < 16; ++r) {
            float ov1 = __shfl_xor(v1s[r], st);
            float ov2 = __shfl_xor(v2s[r], st);
            int   oi1 = __shfl_xor(i1s[r], st);
            v2s[r] = fminf(fminf(v2s[r], ov2), fmaxf(v1s[r], ov1));
            bool c = (ov1 < v1s[r]) || (ov1 == v1s[r] && oi1 < i1s[r]);
            if (c) i1s[r] = oi1;
            v1s[r] = fminf(v1s[r], ov1);
        }
    }
    if (nn == 0) {                                     // lanes 0 and 32 hold 16 rows each
        #pragma unroll
        for (int r = 0; r < 16; ++r) {
            const int row = (r & 3) + 8 * (r >> 2) + 4 * h;
            const int p = w * 32 + row;
            sv1[p] = v1s[r]; si1[p] = i1s[r]; sv2[p] = v2s[r];
        }
    }
    __syncthreads();

    // ---- flag near-ties (waves 0,1 cover points 0..127)
    {
        bool f = (tid < NPB) && ((sv2[tid] - sv1[tid]) < EPSGAP);
        ull bm = __ballot(f);
        if (lane == 0 && w < 2) msk[w] = bm;
    }
    __syncthreads();
    if (tid == 0) {
        int c = 0;
        ull m0 = msk[0];
        while (m0) { lst[1 + c++] = __ffsll(m0) - 1; m0 &= m0 - 1; }
        ull m1 = msk[1];
        while (m1) { lst[1 + c++] = 64 + (__ffsll(m1) - 1); m1 &= m1 - 1; }
        lst[0] = c;
    }
    __syncthreads();

    // ---- exact fp32 rescan, one wave per flagged point (rare: gap < 1e-3)
    const int cnt = lst[0];
    const float4* e4 = (const float4*)emb;
    for (int it = w; it < cnt; it += 4) {
        const int p = lst[1 + it];
        float xv = xbase[lane * HW + p];               // lane d holds x_d (exact fp32)
        float bv = 1e30f; int bk = 0;
        #pragma unroll
        for (int half = 0; half < 2; ++half) {
            float dacc[8];
            #pragma unroll
            for (int j = 0; j < 8; ++j) dacc[j] = 0.f;
            for (int d4 = 0; d4 < 16; ++d4) {
                float x0 = __shfl(xv, d4 * 4 + 0), x1 = __shfl(xv, d4 * 4 + 1);
                float x2 = __shfl(xv, d4 * 4 + 2), x3 = __shfl(xv, d4 * 4 + 3);
                #pragma unroll
                for (int j = 0; j < 8; ++j) {
                    const int k = lane + 64 * (half * 8 + j);
                    float4 e = e4[k * 16 + d4];
                    dacc[j] = fmaf(x0, e.x, dacc[j]); dacc[j] = fmaf(x1, e.y, dacc[j]);
                    dacc[j] = fmaf(x2, e.z, dacc[j]); dacc[j] = fmaf(x3, e.w, dacc[j]);
                }
            }
            #pragma unroll
            for (int j = 0; j < 8; ++j) {              // ascending k per lane: first-min kept
                const int k = lane + 64 * (half * 8 + j);
                float v = hsqw[k] - dacc[j];
                if (v < bv) { bv = v; bk = k; }
            }
        }
        #pragma unroll
        for (int st = 32; st; st >>= 1) {              // 64-wide (v, k) argmin, k tie-break
            float ov = __shfl_xor(bv, st);
            int   ok = __shfl_xor(bk, st);
            if (ov < bv || (ov == bv && ok < bk)) { bv = ov; bk = ok; }
        }
        if (lane == 0) si1[p] = bk;
    }
    __syncthreads();

    // ---- final: indices, quantized gather-write, loss — all 256 threads (32 dims each)
    {
        const int p = tid & 127, dg = tid >> 7;
        const int bi = si1[p];
        if (dg == 0) out[IOFF + n0 + p] = (float)bi;
        const float* e = emb + (size_t)bi * DIMS;
        const float* xp = xbase + p;
        float* oq = out + QOFF + (size_t)b * (DIMS * HW) + off + p;
        float ls = 0.f;
        #pragma unroll
        for (int d0 = 0; d0 < 32; ++d0) {
            const int d = dg * 32 + d0;
            float ev = e[d];
            float xv = xp[d * HW];
            float df = ev - xv;
            ls = fmaf(df, df, ls);
            oq[d * HW] = ev;                           // coalesced across point-threads
        }
        #pragma unroll
        for (int st = 32; st; st >>= 1) ls += __shfl_down(ls, st);
        if (lane == 0) lred[w] = ls;
    }
    __syncthreads();
    if (tid == 0) {
        float s = lred[0] + lred[1] + lred[2] + lred[3];
        atomicAdd(out, s * (0.25f / (float)(NPTS * DIMS)));
    }
}

extern "C" void kernel_launch(void* const* d_in, const int* in_sizes, int n_in,
                              void* d_out, int out_size, void* d_ws, size_t ws_size,
                              hipStream_t stream) {
    const float* in  = (const float*)d_in[0];
    const float* emb = (const float*)d_in[1];
    float* out = (float*)d_out;
    ushort* Eh  = (ushort*)d_ws;                       // 131072 B (tiled fragment order)
    ushort* El  = (ushort*)((char*)d_ws + 131072);     // 131072 B
    float*  hsq = (float*)((char*)d_ws + 262144);      // 4096 B
    (void)in_sizes; (void)n_in; (void)out_size; (void)ws_size;

    vq_prep<<<64, 256, 0, stream>>>(emb, Eh, El, hsq, out);   // also zeroes out[0]
    vq_main<<<NPTS / NPB, 256, 0, stream>>>(in, emb, Eh, El, hsq, out);
}